// Round 4
// baseline (4540.124 us; speedup 1.0000x reference)
//
#include <hip/hip_runtime.h>
#include <stdint.h>
#include <stddef.h>

// Problem constants
constexpr int V = 32000, E = 256, H = 512, B = 64, T = 512;
constexpr int NTHR = 512;        // 8 waves
constexpr int BATG = 16;         // batches per group
constexpr int HPB = 8;           // hidden units per block (32 gate rows)

// LDS offsets (dynamic; request 84KB to pin 1 block/CU)
constexpr int OFF_PS   = 0;                        // 2 x 8 waves x 640 floats
constexpr int OFF_BIAS = OFF_PS + 2 * 8 * 640 * 4; // 40960
constexpr int OFF_LEN  = OFF_BIAS + 32 * 4;        // 41088
constexpr int LDS_BYTES = 84 * 1024;               // force 1 block/CU

// Output layout (flat fp32): output | hT | cT | mask
constexpr size_t OUT_HT   = (size_t)B * T * H;
constexpr size_t OUT_CT   = OUT_HT + (size_t)B * H;
constexpr size_t OUT_MASK = OUT_CT + (size_t)B * H;

typedef __attribute__((ext_vector_type(8))) short short8;   // 8 bf16
typedef __attribute__((ext_vector_type(4))) float f32x4;

__device__ __forceinline__ unsigned short f2bf(float f) {   // RNE fp32->bf16
  uint32_t u = __builtin_bit_cast(uint32_t, f);
  return (unsigned short)((u + 0x7fffu + ((u >> 16) & 1u)) >> 16);
}
__device__ __forceinline__ short8 pack_bf8(float4 v0, float4 v1) {
  short8 r;
  r[0] = (short)f2bf(v0.x); r[1] = (short)f2bf(v0.y);
  r[2] = (short)f2bf(v0.z); r[3] = (short)f2bf(v0.w);
  r[4] = (short)f2bf(v1.x); r[5] = (short)f2bf(v1.y);
  r[6] = (short)f2bf(v1.z); r[7] = (short)f2bf(v1.w);
  return r;
}
__device__ __forceinline__ float sigmoidf_fast(float x) {
  return 1.f / (1.f + __expf(-x));
}
// MALL-coherent relaxed agent ops (bypass per-XCD L2, no cache maintenance)
__device__ __forceinline__ void st_word(uint32_t* p, uint32_t v) {
  __hip_atomic_store(p, v, __ATOMIC_RELAXED, __HIP_MEMORY_SCOPE_AGENT);
}
__device__ __forceinline__ uint32_t ld_word(const uint32_t* p) {
  return __hip_atomic_load(p, __ATOMIC_RELAXED, __HIP_MEMORY_SCOPE_AGENT);
}

__global__ void __launch_bounds__(NTHR, 1)
lstm_mfma(const int* __restrict__ inputs, const int* __restrict__ lengths,
          const int* __restrict__ resets, const float* __restrict__ emb,
          const float* __restrict__ W_ih, const float* __restrict__ W_hh,
          const float* __restrict__ b_ih, const float* __restrict__ b_hh,
          float* __restrict__ out, int* __restrict__ ctr,
          uint32_t* __restrict__ hw) {
  extern __shared__ char lds[];
  float* Ps = (float*)(lds + OFF_PS);     // [step&1][wave][n(32)*20 + m(16)]
  float* Bias = (float*)(lds + OFF_BIAS);
  int* Lens = (int*)(lds + OFF_LEN);

  const int tid = threadIdx.x;
  const int blk = blockIdx.x;
  const int grp = blk & 3;        // batch group
  const int rq = blk >> 2;        // row chunk 0..63
  const int khid = rq * HPB;
  const int b0 = grp * BATG;

  const int w = tid >> 6;         // wave 0..7 : K-slice [96w, 96w+96)
  const int L = tid & 63;
  const int lc = L & 15;          // A: batch m | B/D: col n within tile
  const int q = L >> 4;           // quad

  // ---- persistent W fragments (bf16): wf[tile][s]
  short8 wf[2][3];
  #pragma unroll
  for (int tl = 0; tl < 2; ++tl) {
    #pragma unroll
    for (int s = 0; s < 3; ++s) {
      const int kk = 96 * w + 32 * s + 8 * q;
      const int n = 16 * tl + lc;
      const int grow = (n >> 3) * H + khid + (n & 7);
      const float* src = (kk < 512) ? (W_hh + (size_t)grow * H + kk)
                                    : (W_ih + (size_t)grow * E + (kk - 512));
      float4 v0 = *(const float4*)src;
      float4 v1 = *(const float4*)(src + 4);
      wf[tl][s] = pack_bf8(v0, v1);
    }
  }
  if (tid < 32) {
    const int grow = (tid >> 3) * H + khid + (tid & 7);
    Bias[tid] = b_ih[grow] + b_hh[grow];
  }
  if (tid < 16) Lens[tid] = lengths[b0 + tid];

  const int jj = tid >> 4;        // epilogue ids (tid<128 only): hidden j 0..7
  const int bb = tid & 15;        // batch 0..15

  // mask output (fused; 128 elements per block)
  if (tid < 128) {
    int i = blk * 128 + tid;
    int mb = i >> 9, mt = i & (T - 1);
    out[OUT_MASK + i] = (mt < lengths[mb]) ? 1.f : 0.f;
  }
  // clear stale tags in our own h-word slices (both ping-pong buffers)
  if (tid < 128) {
    st_word(&hw[(size_t)(b0 + bb) * H + khid + jj], 0u);
    st_word(&hw[(size_t)(B * H) + (size_t)(b0 + bb) * H + khid + jj], 0u);
  }
  // ---- one-time global barrier (all 256 blocks): tag-clears visible
  __syncthreads();
  if (tid == 0) {
    __hip_atomic_fetch_add(ctr, 1, __ATOMIC_RELEASE, __HIP_MEMORY_SCOPE_AGENT);
    while (__hip_atomic_load(ctr, __ATOMIC_RELAXED, __HIP_MEMORY_SCOPE_AGENT) < 256)
      __builtin_amdgcn_s_sleep(1);
    __builtin_amdgcn_fence(__ATOMIC_ACQUIRE, "agent");
  }
  __syncthreads();

  float carry_h = 0.f, carry_c = 0.f;

  for (int t = 0; t < T; ++t) {
    uint32_t* src_base = hw + (size_t)(t & 1) * (B * H);
    uint32_t* dst_base = hw + (size_t)((t + 1) & 1) * (B * H);
    float* Pcur = Ps + (t & 1) * (8 * 640);

    // ---- pre-poll independent work
    float rr = 0.f;
    if (tid < 128) rr = (float)resets[(b0 + bb) * T + t];
    const int tok = inputs[(b0 + lc) * T + t];
    short8 afrag[3];
    bool ish[3];
    #pragma unroll
    for (int s = 0; s < 3; ++s) {
      const int kk = 96 * w + 32 * s + 8 * q;
      ish[s] = (kk < 512);
      if (!ish[s]) {              // emb side: t-dependent only, issue early
        const float* src = emb + (size_t)tok * E + (kk - 512);
        afrag[s] = pack_bf8(*(const float4*)src, *(const float4*)(src + 4));
      }
    }

    // ---- h side: poll self-validating tagged words, then MFMA
    f32x4 acc0 = {0.f, 0.f, 0.f, 0.f};
    f32x4 acc1 = {0.f, 0.f, 0.f, 0.f};
    #pragma unroll
    for (int s = 0; s < 3; ++s) {
      const int kk = 96 * w + 32 * s + 8 * q;
      if (ish[s] && t > 0) {
        const uint32_t* p = src_base + (size_t)(b0 + lc) * H + kk;
        uint32_t wv[8];
        for (;;) {
          bool ok = true;
          #pragma unroll
          for (int j = 0; j < 8; ++j) wv[j] = ld_word(p + j);
          #pragma unroll
          for (int j = 0; j < 8; ++j) ok &= ((wv[j] >> 16) == (uint32_t)t);
          if (__all(ok)) break;
          __builtin_amdgcn_s_sleep(1);
        }
        short8 a;
        #pragma unroll
        for (int j = 0; j < 8; ++j) a[j] = (short)(wv[j] & 0xffffu);
        afrag[s] = a;
      }
      if (!ish[s] || t > 0) {     // t==0: h contribution is zero, skip
        acc0 = __builtin_amdgcn_mfma_f32_16x16x32_bf16(afrag[s], wf[0][s], acc0, 0, 0, 0);
        acc1 = __builtin_amdgcn_mfma_f32_16x16x32_bf16(afrag[s], wf[1][s], acc1, 0, 0, 0);
      }
    }
    // partials: D[m=4q+r][n] -> Pcur[w*640 + n*20 + m]
    *(f32x4*)(Pcur + w * 640 + lc * 20 + 4 * q) = acc0;
    *(f32x4*)(Pcur + w * 640 + (16 + lc) * 20 + 4 * q) = acc1;
    __syncthreads();              // the ONLY per-step block sync

    // ---- fused reduce + activations + state update (128 threads)
    if (tid < 128) {
      float g4[4];
      #pragma unroll
      for (int gi = 0; gi < 4; ++gi) {
        const int n = gi * 8 + jj;
        float s = Bias[n];
        #pragma unroll
        for (int ww = 0; ww < 8; ++ww) s += Pcur[ww * 640 + n * 20 + bb];
        g4[gi] = s;
      }
      float ig = sigmoidf_fast(g4[0]);
      float fg = sigmoidf_fast(g4[1]);
      float gg = tanhf(g4[2]);
      float og = sigmoidf_fast(g4[3]);
      float c_new = fg * carry_c + ig * gg;
      float h_new = og * tanhf(c_new);
      bool live = (t < Lens[bb]);
      float h_next = live ? h_new : carry_h;   // carry regs are exact fp32
      float c_next = live ? c_new : carry_c;
      carry_h = h_next * (1.f - rr);
      carry_c = c_next * (1.f - rr);
      // post h word FIRST (critical path), then the HBM output store
      uint32_t word = ((uint32_t)(t + 1) << 16) | (uint32_t)f2bf(carry_h);
      st_word(dst_base + (size_t)(b0 + bb) * H + khid + jj, word);
      out[((size_t)(b0 + bb) * T + t) * H + khid + jj] = h_next;
    }
    // No trailing sync: next step's Ps buffer is the other half (double-buffered),
    // and overwrite of h words is throttled by the tag poll itself.
  }
  if (tid < 128) {
    out[OUT_HT + (size_t)(b0 + bb) * H + khid + jj] = carry_h;
    out[OUT_CT + (size_t)(b0 + bb) * H + khid + jj] = carry_c;
  }
}

extern "C" void kernel_launch(void* const* d_in, const int* in_sizes, int n_in,
                              void* d_out, int out_size, void* d_ws, size_t ws_size,
                              hipStream_t stream) {
  const int* inputs    = (const int*)d_in[0];
  const int* lengths   = (const int*)d_in[1];
  const int* resets    = (const int*)d_in[2];
  const float* emb     = (const float*)d_in[3];
  const float* W_ih    = (const float*)d_in[4];
  const float* W_hh    = (const float*)d_in[5];
  const float* b_ih    = (const float*)d_in[6];
  const float* b_hh    = (const float*)d_in[7];
  float* out = (float*)d_out;

  // ws layout: [0,4096): init-barrier counter; [4096, +256KB): tagged h words
  int* ctr = (int*)d_ws;
  uint32_t* hw = (uint32_t*)((char*)d_ws + 4096);

  hipFuncSetAttribute((const void*)lstm_mfma,
                      hipFuncAttributeMaxDynamicSharedMemorySize, LDS_BYTES);

  hipMemsetAsync(d_ws, 0, 4096, stream);  // init-barrier counter = 0
  lstm_mfma<<<256, NTHR, LDS_BYTES, stream>>>(
      inputs, lengths, resets, emb, W_ih, W_hh, b_ih, b_hh, out, ctr, hw);
}

// Round 5
// 2056.191 us; speedup vs baseline: 2.2080x; 2.2080x over previous
//
#include <hip/hip_runtime.h>
#include <stdint.h>
#include <stddef.h>

// Problem constants
constexpr int V = 32000, E = 256, H = 512, B = 64, T = 512;
constexpr int NTHR = 512;        // 8 waves
constexpr int NBLK = 64;         // 4 groups x 16 blocks
constexpr int BATG = 16;         // batches per group
constexpr int HPB = 32;         // hidden units per block (128 gate rows)

// LDS: Ps [8 waves][128 rows * 17 + pad]
constexpr int PSW = 128 * 17;                       // 2176 floats per wave
constexpr int OFF_PS   = 0;                         // 8*2176*4 = 69632
constexpr int OFF_BIAS = OFF_PS + 8 * PSW * 4;      // 69632
constexpr int OFF_LEN  = OFF_BIAS + 128 * 4;        // 70144
constexpr int LDS_BYTES = 84 * 1024;                // force 1 block/CU

// Output layout (flat fp32): output | hT | cT | mask
constexpr size_t OUT_HT   = (size_t)B * T * H;
constexpr size_t OUT_CT   = OUT_HT + (size_t)B * H;
constexpr size_t OUT_MASK = OUT_CT + (size_t)B * H;

typedef __attribute__((ext_vector_type(8))) short short8;   // 8 bf16
typedef __attribute__((ext_vector_type(4))) float f32x4;
typedef __attribute__((ext_vector_type(4))) unsigned int u32x4;

__device__ __forceinline__ unsigned short f2bf(float f) {   // RNE fp32->bf16
  uint32_t u = __builtin_bit_cast(uint32_t, f);
  return (unsigned short)((u + 0x7fffu + ((u >> 16) & 1u)) >> 16);
}
__device__ __forceinline__ short8 pack_bf8(float4 v0, float4 v1) {
  short8 r;
  r[0] = (short)f2bf(v0.x); r[1] = (short)f2bf(v0.y);
  r[2] = (short)f2bf(v0.z); r[3] = (short)f2bf(v0.w);
  r[4] = (short)f2bf(v1.x); r[5] = (short)f2bf(v1.y);
  r[6] = (short)f2bf(v1.z); r[7] = (short)f2bf(v1.w);
  return r;
}
__device__ __forceinline__ float sigmoidf_fast(float x) {
  return 1.f / (1.f + __expf(-x));
}
__device__ __forceinline__ float tanhf_fast(float x) {   // 1 - 2/(e^2x+1)
  return 1.f - 2.f / (__expf(2.f * x) + 1.f);            // inf-safe both tails
}
// MALL-coherent relaxed agent ops (device scope; bypass per-XCD L2)
__device__ __forceinline__ void st_word(uint32_t* p, uint32_t v) {
  __hip_atomic_store(p, v, __ATOMIC_RELAXED, __HIP_MEMORY_SCOPE_AGENT);
}
// 4x dwordx4 device-scope loads, one address reg + imm offsets, single wait
__device__ __forceinline__ void ld_mall_4x4(const uint32_t* p, u32x4& r0,
                                            u32x4& r1, u32x4& r2, u32x4& r3) {
  asm volatile(
      "global_load_dwordx4 %0, %4, off sc1\n\t"
      "global_load_dwordx4 %1, %4, off offset:64 sc1\n\t"
      "global_load_dwordx4 %2, %4, off offset:128 sc1\n\t"
      "global_load_dwordx4 %3, %4, off offset:192 sc1\n\t"
      "s_waitcnt vmcnt(0)"
      : "=&v"(r0), "=&v"(r1), "=&v"(r2), "=&v"(r3)
      : "v"(p)
      : "memory");
}

__global__ void __launch_bounds__(NTHR, 1)
lstm_mfma(const int* __restrict__ inputs, const int* __restrict__ lengths,
          const int* __restrict__ resets, const float* __restrict__ emb,
          const float* __restrict__ W_ih, const float* __restrict__ W_hh,
          const float* __restrict__ b_ih, const float* __restrict__ b_hh,
          float* __restrict__ out, int* __restrict__ ctr,
          uint32_t* __restrict__ hw) {
  extern __shared__ char lds[];
  float* Ps = (float*)(lds + OFF_PS);     // [wave][n(128)*17 + m(16)]
  float* Bias = (float*)(lds + OFF_BIAS);
  int* Lens = (int*)(lds + OFF_LEN);

  const int tid = threadIdx.x;
  const int blk = blockIdx.x;
  const int grp = blk & 3;        // batch group 0..3
  const int rq = blk >> 2;        // block rank in group 0..15
  const int khid = rq * HPB;      // hidden base (32 dims)
  const int b0 = grp * BATG;
  int* flags = ctr + grp * 64;    // 16 dwords used; one cacheline per group

  const int w = tid >> 6;         // wave 0..7
  const int L = tid & 63;
  const int lc = L & 15;          // A: batch m | B: gate row n within tile
  const int q = L >> 4;           // quad

  // ---- persistent W fragments (bf16): wf[s][tile]
  // waves 0..3: h side, K = 128w + 32s + 8q (4 frags)
  // waves 4..7: emb side, Ke = 64(w-4) + 32s + 8q (2 frags)
  short8 wf[4][8];
  if (w < 4) {
    #pragma unroll
    for (int s = 0; s < 4; ++s) {
      #pragma unroll
      for (int tl = 0; tl < 8; ++tl) {
        const int n = 16 * tl + lc;
        const int grow = (n >> 5) * H + khid + (n & 31);
        const float* src = W_hh + (size_t)grow * H + 128 * w + 32 * s + 8 * q;
        wf[s][tl] = pack_bf8(*(const float4*)src, *(const float4*)(src + 4));
      }
    }
  } else {
    #pragma unroll
    for (int s = 0; s < 2; ++s) {
      #pragma unroll
      for (int tl = 0; tl < 8; ++tl) {
        const int n = 16 * tl + lc;
        const int grow = (n >> 5) * H + khid + (n & 31);
        const float* src = W_ih + (size_t)grow * E + 64 * (w - 4) + 32 * s + 8 * q;
        wf[s][tl] = pack_bf8(*(const float4*)src, *(const float4*)(src + 4));
      }
    }
  }
  if (tid < 128) {
    const int grow = (tid >> 5) * H + khid + (tid & 31);
    Bias[tid] = b_ih[grow] + b_hh[grow];
  }
  if (tid < 16) Lens[tid] = lengths[b0 + tid];
  {  // mask output, fused: 64 blocks x 512 threads = B*T
    int i = blk * 512 + tid;
    int mb = i >> 9, mt = i & (T - 1);
    out[OUT_MASK + i] = (mt < lengths[mb]) ? 1.f : 0.f;
  }
  __syncthreads();

  const int jj = tid & 31;        // epilogue: hidden 0..31 (contig per wave)
  const int bb = tid >> 5;        // batch 0..15

  float carry_h = 0.f, carry_c = 0.f;

  for (int t = 0; t < T; ++t) {
    const uint32_t* hsrc = hw + (size_t)(t & 1) * (B * 256);
    uint32_t* hdst = hw + (size_t)((t + 1) & 1) * (B * 256);

    // ---- pre-barrier independent work
    float rr = (float)resets[(b0 + bb) * T + t];
    f32x4 acc[8];
    #pragma unroll
    for (int tl = 0; tl < 8; ++tl) acc[tl] = (f32x4){0.f, 0.f, 0.f, 0.f};

    if (w >= 4) {                 // emb side: fully pre-barrier
      const int tok = inputs[(b0 + lc) * T + t];
      const float* eb = emb + (size_t)tok * E + 64 * (w - 4) + 8 * q;
      short8 a0 = pack_bf8(*(const float4*)eb, *(const float4*)(eb + 4));
      short8 a1 = pack_bf8(*(const float4*)(eb + 32), *(const float4*)(eb + 36));
      #pragma unroll
      for (int tl = 0; tl < 8; ++tl)
        acc[tl] = __builtin_amdgcn_mfma_f32_16x16x32_bf16(a0, wf[0][tl], acc[tl], 0, 0, 0);
      #pragma unroll
      for (int tl = 0; tl < 8; ++tl)
        acc[tl] = __builtin_amdgcn_mfma_f32_16x16x32_bf16(a1, wf[1][tl], acc[tl], 0, 0, 0);
    }

    if (t > 0) {
      // ---- flag barrier: wave 0 polls this group's 16 flags (1 cacheline)
      if (w == 0) {
        for (;;) {
          int v = 0x7fffffff;
          if (L < 16) v = __hip_atomic_load(&flags[L], __ATOMIC_RELAXED,
                                            __HIP_MEMORY_SCOPE_AGENT);
          if (__all(v >= t)) break;
          __builtin_amdgcn_s_sleep(1);
        }
      }
      __syncthreads();
      if (w < 4) {                // h side: one dwordx4 per frag, MALL-coherent
        const uint32_t* p = hsrc + (size_t)(b0 + lc) * 256 + 64 * w + 4 * q;
        u32x4 r0, r1, r2, r3;
        ld_mall_4x4(p, r0, r1, r2, r3);
        short8 a0 = __builtin_bit_cast(short8, r0);
        short8 a1 = __builtin_bit_cast(short8, r1);
        short8 a2 = __builtin_bit_cast(short8, r2);
        short8 a3 = __builtin_bit_cast(short8, r3);
        #pragma unroll
        for (int tl = 0; tl < 8; ++tl)
          acc[tl] = __builtin_amdgcn_mfma_f32_16x16x32_bf16(a0, wf[0][tl], acc[tl], 0, 0, 0);
        #pragma unroll
        for (int tl = 0; tl < 8; ++tl)
          acc[tl] = __builtin_amdgcn_mfma_f32_16x16x32_bf16(a1, wf[1][tl], acc[tl], 0, 0, 0);
        #pragma unroll
        for (int tl = 0; tl < 8; ++tl)
          acc[tl] = __builtin_amdgcn_mfma_f32_16x16x32_bf16(a2, wf[2][tl], acc[tl], 0, 0, 0);
        #pragma unroll
        for (int tl = 0; tl < 8; ++tl)
          acc[tl] = __builtin_amdgcn_mfma_f32_16x16x32_bf16(a3, wf[3][tl], acc[tl], 0, 0, 0);
      }
    }

    // partials: D[m=4q+reg][n=16tl+lc] -> Ps[w*PSW + n*17 + m]
    #pragma unroll
    for (int tl = 0; tl < 8; ++tl)
      *(f32x4*)(Ps + w * PSW + (16 * tl + lc) * 17 + 4 * q) = acc[tl];
    __syncthreads();

    // ---- fused reduce + activations + state update (all 512 threads)
    float g4[4];
    #pragma unroll
    for (int gi = 0; gi < 4; ++gi) {
      const int n = gi * 32 + jj;
      float s = Bias[n];
      #pragma unroll
      for (int ww = 0; ww < 8; ++ww) s += Ps[ww * PSW + n * 17 + bb];
      g4[gi] = s;
    }
    float ig = sigmoidf_fast(g4[0]);
    float fg = sigmoidf_fast(g4[1]);
    float gg = tanhf_fast(g4[2]);
    float og = sigmoidf_fast(g4[3]);
    float c_new = fg * carry_c + ig * gg;
    float h_new = og * tanhf_fast(c_new);
    bool live = (t < Lens[bb]);
    float h_next = live ? h_new : carry_h;   // carry regs are exact fp32
    float c_next = live ? c_new : carry_c;
    carry_h = h_next * (1.f - rr);
    carry_c = c_next * (1.f - rr);

    // pack 2 adjacent hidden dims per dword; even lanes store
    float ph = __shfl(carry_h, L ^ 1);
    if (t < T - 1) {
      if ((tid & 1) == 0) {
        uint32_t word = (uint32_t)f2bf(carry_h) | ((uint32_t)f2bf(ph) << 16);
        st_word(hdst + (size_t)(b0 + bb) * 256 + 16 * rq + (jj >> 1), word);
      }
      __syncthreads();            // drains vmcnt: all h words MALL-acked
      if (tid == 0)
        __hip_atomic_store(&flags[rq], t + 1, __ATOMIC_RELAXED,
                           __HIP_MEMORY_SCOPE_AGENT);
    }
    // HBM output store off the critical path
    out[((size_t)(b0 + bb) * T + t) * H + khid + jj] = h_next;
  }
  out[OUT_HT + (size_t)(b0 + bb) * H + khid + jj] = carry_h;
  out[OUT_CT + (size_t)(b0 + bb) * H + khid + jj] = carry_c;
}

extern "C" void kernel_launch(void* const* d_in, const int* in_sizes, int n_in,
                              void* d_out, int out_size, void* d_ws, size_t ws_size,
                              hipStream_t stream) {
  const int* inputs    = (const int*)d_in[0];
  const int* lengths   = (const int*)d_in[1];
  const int* resets    = (const int*)d_in[2];
  const float* emb     = (const float*)d_in[3];
  const float* W_ih    = (const float*)d_in[4];
  const float* W_hh    = (const float*)d_in[5];
  const float* b_ih    = (const float*)d_in[6];
  const float* b_hh    = (const float*)d_in[7];
  float* out = (float*)d_out;

  // ws layout: [0,4096): flags; [4096, +128KB): bf16-pair h ping-pong words
  int* ctr = (int*)d_ws;
  uint32_t* hw = (uint32_t*)((char*)d_ws + 4096);

  hipFuncSetAttribute((const void*)lstm_mfma,
                      hipFuncAttributeMaxDynamicSharedMemorySize, LDS_BYTES);

  hipMemsetAsync(d_ws, 0, 4096, stream);  // flags = 0
  lstm_mfma<<<NBLK, NTHR, LDS_BYTES, stream>>>(
      inputs, lengths, resets, emb, W_ih, W_hh, b_ih, b_hh, out, ctr, hw);
}